// Round 18
// baseline (188.904 us; speedup 1.0000x reference)
//
#include <hip/hip_runtime.h>

// ---------------------------------------------------------------- constants
static constexpr int Bn   = 8;
static constexpr int S    = 1024;
static constexpr int FT   = 16;
static constexpr int FDZ  = 768;
static constexpr int INK  = 784;   // FDZ + FT
static constexpr int FDEC = 1024;
static constexpr int M    = Bn * S;   // 8192 rows
static constexpr int H    = 16;
static constexpr int FD   = 16;

typedef __bf16 bf16x8 __attribute__((ext_vector_type(8)));
typedef float  f32x4  __attribute__((ext_vector_type(4)));

__device__ __forceinline__ unsigned short f2b(float f) {
  return __builtin_bit_cast(unsigned short, static_cast<__bf16>(f));
}
__device__ __forceinline__ float b2f(unsigned short u) {
  return (float)__builtin_bit_cast(__bf16, u);
}

__device__ __forceinline__ void gload16(const void* g, void* l) {
  __builtin_amdgcn_global_load_lds(
      (const __attribute__((address_space(1))) unsigned int*)g,
      (__attribute__((address_space(3))) unsigned int*)l, 16, 0, 0);
}

// ---------------------------------------------------------------- merged pre-pass (1 launch)
// [0,3072) w3 | [3072,3088) dwb | [3088,3091) b3 | [3091,3155) wt16 |
// [3155,3219) wcomb part | [3219] bias2 | [3220,5268) za
__global__ __launch_bounds__(256) void k_pre(const float* __restrict__ dnw,
                                             const float* __restrict__ wq,
                                             const float* __restrict__ wk,
                                             const float* __restrict__ wv,
                                             const float* __restrict__ wo,
                                             const float* __restrict__ dcw,
                                             const float* __restrict__ bq,
                                             const float* __restrict__ bk,
                                             const float* __restrict__ bv,
                                             const float* __restrict__ bo,
                                             const float* __restrict__ dcb,
                                             const float* __restrict__ z,
                                             unsigned short* __restrict__ w3,
                                             unsigned short* __restrict__ dwb,
                                             float* __restrict__ b3,
                                             unsigned short* __restrict__ wt16,
                                             float* __restrict__ part,
                                             float* __restrict__ bias2,
                                             float* __restrict__ za) {
  const int bid = blockIdx.x, tid = threadIdx.x;
  const int c = tid * 4;
  if (bid < 3072) {
    const int r = bid;
    const float* src = (r < 1024) ? wq : (r < 2048 ? wk : wv);
    const int rr = r & 1023;
    float4 v = *reinterpret_cast<const float4*>(&src[(size_t)rr * 1024 + c]);
    unsigned short o4[4] = {f2b(v.x), f2b(v.y), f2b(v.z), f2b(v.w)};
    *reinterpret_cast<uint2*>(&w3[(size_t)r * 1024 + c]) = *reinterpret_cast<uint2*>(o4);
  } else if (bid < 3088) {
    const int r = bid - 3072;
    float4 v = *reinterpret_cast<const float4*>(&dcw[(size_t)r * 1024 + c]);
    unsigned short o4[4] = {f2b(v.x), f2b(v.y), f2b(v.z), f2b(v.w)};
    *reinterpret_cast<uint2*>(&dwb[(size_t)r * 1024 + c]) = *reinterpret_cast<uint2*>(o4);
  } else if (bid < 3091) {
    const int r = bid - 3088;
    const float* s = (r == 0) ? bq : (r == 1 ? bk : bv);
    *reinterpret_cast<float4*>(&b3[r * 1024 + c]) =
        *reinterpret_cast<const float4*>(&s[c]);
  } else if (bid < 3155) {
    const int idx = (bid - 3091) * 256 + tid;   // 0..16383
    const int k = idx >> 10, cc = idx & 1023;
    wt16[k * 1024 + cc] = f2b(dnw[(size_t)cc * INK + k]);
  } else if (bid < 3219) {
    // wcomb stage 1, coalesced: part[kb][i][:] += dcw[i][16kb+k] * wo[16kb+k][:]
    const int kb = bid - 3155;
    const int k0 = kb * 16;
    float4 wv4[16];
#pragma unroll
    for (int k = 0; k < 16; k++)
      wv4[k] = *reinterpret_cast<const float4*>(&wo[(size_t)(k0 + k) * 1024 + c]);
#pragma unroll
    for (int i = 0; i < 16; i++) {
      float4 a = make_float4(0.f, 0.f, 0.f, 0.f);
#pragma unroll
      for (int k = 0; k < 16; k++) {
        float d = dcw[i * 1024 + k0 + k];   // uniform -> scalar load
        a.x += d * wv4[k].x; a.y += d * wv4[k].y;
        a.z += d * wv4[k].z; a.w += d * wv4[k].w;
      }
      *reinterpret_cast<float4*>(&part[((size_t)kb * 16 + i) * 1024 + c]) = a;
    }
  } else if (bid < 3220) {
    const int lane = tid & 63, w = tid >> 6;
    for (int q = 0; q < 4; q++) {
      int f = w * 4 + q;
      const float* dp = &dcw[(size_t)f * 1024];
      float s = 0.f;
#pragma unroll
      for (int t = 0; t < 16; t++) {
        int k = lane + t * 64;
        s += dp[k] * bo[k];
      }
      for (int off = 32; off; off >>= 1) s += __shfl_down(s, off);
      if (lane == 0) bias2[f] = s + dcb[f];
    }
  } else {
    const int lane = tid & 63, w = tid >> 6;
    const int idx = (bid - 3220) * 4 + w;        // 0..8191
    const int col = idx >> 3, b = idx & 7;
    const float* wp = &dnw[(size_t)col * INK + FT];
    const float* zp = &z[b * FDZ];
    float s = 0.f;
#pragma unroll
    for (int i = 0; i < 12; i++) {
      int k = lane + i * 64;
      s += wp[k] * zp[k];
    }
    for (int off = 32; off; off >>= 1) s += __shfl_down(s, off);
    if (lane == 0) za[b * 1024 + col] = s;
  }
}

// ---------------------------------------------------------------- dense(K=16)+LN  +  wcomb reduce
// bid < 2048: dense+LN (4 rows/block). bid in [2048,2112): wcomb stage-2 reduce.
__global__ __launch_bounds__(256) void k_dln(const float* __restrict__ rt,
                                             const float* __restrict__ za,
                                             const float* __restrict__ dnb,
                                             const float* __restrict__ lng,
                                             const float* __restrict__ lnb,
                                             const unsigned short* __restrict__ wt16g,
                                             const float* __restrict__ part,
                                             unsigned short* __restrict__ xres,
                                             unsigned short* __restrict__ xn,
                                             unsigned short* __restrict__ wcombb) {
  const int tid = threadIdx.x;
  if (blockIdx.x >= 2048) {
    const int idx = (blockIdx.x - 2048) * 256 + tid;   // 0..16383
    float s = 0.f;
#pragma unroll 8
    for (int kb = 0; kb < 64; kb++) s += part[(size_t)kb * 16384 + idx];
    wcombb[idx] = f2b(s);
    return;
  }
  __shared__ unsigned short wt[16 * 1024];     // [k][c] bf16, 32 KiB
  __shared__ float ss[4], qq[4];
  const int lane = tid & 63, wv = tid >> 6;
  const int c0 = tid * 4;
#pragma unroll
  for (int i = 0; i < 8; i++)
    reinterpret_cast<uint4*>(wt)[tid + 256 * i] =
        reinterpret_cast<const uint4*>(wt16g)[tid + 256 * i];
  const float4 bv  = *reinterpret_cast<const float4*>(&dnb[c0]);
  const float4 gv  = *reinterpret_cast<const float4*>(&lng[c0]);
  const float4 bev = *reinterpret_cast<const float4*>(&lnb[c0]);
  __syncthreads();

  for (int r = 0; r < 4; ++r) {
    const int m = blockIdx.x * 4 + r;
    const int b = m >> 10;
    float rtv[16];
    {
      float4 t0 = *reinterpret_cast<const float4*>(&rt[m * 16 + 0]);
      float4 t1 = *reinterpret_cast<const float4*>(&rt[m * 16 + 4]);
      float4 t2 = *reinterpret_cast<const float4*>(&rt[m * 16 + 8]);
      float4 t3 = *reinterpret_cast<const float4*>(&rt[m * 16 + 12]);
      rtv[0]=t0.x; rtv[1]=t0.y; rtv[2]=t0.z; rtv[3]=t0.w;
      rtv[4]=t1.x; rtv[5]=t1.y; rtv[6]=t1.z; rtv[7]=t1.w;
      rtv[8]=t2.x; rtv[9]=t2.y; rtv[10]=t2.z; rtv[11]=t2.w;
      rtv[12]=t3.x; rtv[13]=t3.y; rtv[14]=t3.z; rtv[15]=t3.w;
    }
    float4 zav = *reinterpret_cast<const float4*>(&za[b * 1024 + c0]);
    float acc[4] = {zav.x + bv.x, zav.y + bv.y, zav.z + bv.z, zav.w + bv.w};
#pragma unroll
    for (int k = 0; k < 16; ++k) {
      uint2 wraw = *reinterpret_cast<const uint2*>(&wt[k * 1024 + c0]);
      const unsigned short* wp = reinterpret_cast<const unsigned short*>(&wraw);
      float rk = rtv[k];
      acc[0] += rk * b2f(wp[0]);
      acc[1] += rk * b2f(wp[1]);
      acc[2] += rk * b2f(wp[2]);
      acc[3] += rk * b2f(wp[3]);
    }
    float s = acc[0] + acc[1] + acc[2] + acc[3];
    float q = acc[0]*acc[0] + acc[1]*acc[1] + acc[2]*acc[2] + acc[3]*acc[3];
    for (int off = 32; off; off >>= 1) { s += __shfl_down(s, off); q += __shfl_down(q, off); }
    if (lane == 0) { ss[wv] = s; qq[wv] = q; }
    __syncthreads();
    float St = ss[0] + ss[1] + ss[2] + ss[3];
    float Qt = qq[0] + qq[1] + qq[2] + qq[3];
    float mu  = St * (1.f / 1024.f);
    float var = Qt * (1.f / 1024.f) - mu * mu;
    float rstd = rsqrtf(var + 1e-6f);
    unsigned short xo[4], no[4];
    xo[0] = f2b(acc[0]); no[0] = f2b(gv.x * (acc[0] - mu) * rstd + bev.x);
    xo[1] = f2b(acc[1]); no[1] = f2b(gv.y * (acc[1] - mu) * rstd + bev.y);
    xo[2] = f2b(acc[2]); no[2] = f2b(gv.z * (acc[2] - mu) * rstd + bev.z);
    xo[3] = f2b(acc[3]); no[3] = f2b(gv.w * (acc[3] - mu) * rstd + bev.w);
    *reinterpret_cast<uint2*>(&xres[(size_t)m * 1024 + c0]) = *reinterpret_cast<uint2*>(xo);
    *reinterpret_cast<uint2*>(&xn[(size_t)m * 1024 + c0])   = *reinterpret_cast<uint2*>(no);
    __syncthreads();
  }
}

// ---------------------------------------------------------------- GEMM 128x128 (qkv)
template<int EPI>
__global__ __launch_bounds__(256, 3) void k_gemm1(const unsigned short* __restrict__ A, int lda,
                                                  const unsigned short* __restrict__ Bw, int ldb,
                                                  int K, int N,
                                                  const float* __restrict__ bias,
                                                  unsigned short* __restrict__ Cb) {
  __shared__ __align__(16) unsigned short As[3 * 128 * 32];   // 24 KiB
  __shared__ __align__(16) unsigned short Bs[3 * 128 * 32];   // 24 KiB
  const int tid = threadIdx.x, lane = tid & 63, w = tid >> 6;
  const int wr = w >> 1, wc = w & 1;
  const int lr = lane & 15, lg = lane >> 4;

  const int xcd = blockIdx.x & 7;
  const int j   = blockIdx.x >> 3;
  const int m0  = (xcd * 8 + (j & 7)) * 128;
  const int n0  = (j >> 3) * 128;

  const int nt = K >> 5;

  const int g0 = tid;
  const int r0g = g0 >> 2, c0g = (g0 & 3) ^ ((r0g >> 1) & 3);
  const int g1 = tid + 256;
  const int r1g = g1 >> 2, c1g = (g1 & 3) ^ ((r1g >> 1) & 3);
  const unsigned short* srcA0 = A + (size_t)(m0 + r0g) * lda + c0g * 8;
  const unsigned short* srcA1 = A + (size_t)(m0 + r1g) * lda + c1g * 8;
  const unsigned short* srcB0 = Bw + (size_t)(n0 + r0g) * ldb + c0g * 8;
  const unsigned short* srcB1 = Bw + (size_t)(n0 + r1g) * ldb + c1g * 8;
  const int d0 = (w * 64) * 8;
  const int d1 = (256 + w * 64) * 8;

  int offA[4], offB[4];
#pragma unroll
  for (int mi = 0; mi < 4; mi++) {
    int r = wr * 64 + mi * 16 + lr;
    offA[mi] = r * 32 + (lg ^ ((r >> 1) & 3)) * 8;
  }
#pragma unroll
  for (int ni = 0; ni < 4; ni++) {
    int r = wc * 64 + ni * 16 + lr;
    offB[ni] = r * 32 + (lg ^ ((r >> 1) & 3)) * 8;
  }

  f32x4 acc[4][4];
#pragma unroll
  for (int i = 0; i < 4; i++)
#pragma unroll
    for (int j2 = 0; j2 < 4; j2++)
#pragma unroll
      for (int e = 0; e < 4; e++) acc[i][j2][e] = 0.f;

  auto stage = [&](int tt) {
    const int sl = tt % 3;
    const size_t ko = (size_t)tt * 32;
    gload16(srcA0 + ko, &As[sl * 4096 + d0]);
    gload16(srcA1 + ko, &As[sl * 4096 + d1]);
    gload16(srcB0 + ko, &Bs[sl * 4096 + d0]);
    gload16(srcB1 + ko, &Bs[sl * 4096 + d1]);
  };
  auto compute = [&](int tt) {
    const int sl = (tt % 3) * 4096;
    bf16x8 af[4], bfr[4];
#pragma unroll
    for (int mi = 0; mi < 4; mi++)
      af[mi] = *reinterpret_cast<const bf16x8*>(&As[sl + offA[mi]]);
#pragma unroll
    for (int ni = 0; ni < 4; ni++)
      bfr[ni] = *reinterpret_cast<const bf16x8*>(&Bs[sl + offB[ni]]);
    __builtin_amdgcn_s_setprio(1);
#pragma unroll
    for (int mi = 0; mi < 4; mi++)
#pragma unroll
      for (int ni = 0; ni < 4; ni++)
        acc[mi][ni] = __builtin_amdgcn_mfma_f32_16x16x32_bf16(af[mi], bfr[ni], acc[mi][ni], 0, 0, 0);
    __builtin_amdgcn_s_setprio(0);
  };

  stage(0); stage(1);

  int t = 0;
  for (; t < nt - 2; ++t) {
    asm volatile("s_waitcnt vmcnt(4)" ::: "memory");
    __builtin_amdgcn_s_barrier();
    stage(t + 2);
    compute(t);
  }
  asm volatile("s_waitcnt vmcnt(4)" ::: "memory");
  __builtin_amdgcn_s_barrier();
  compute(t); ++t;
  asm volatile("s_waitcnt vmcnt(0)" ::: "memory");
  __builtin_amdgcn_s_barrier();
  compute(t);

#pragma unroll
  for (int mi = 0; mi < 4; mi++)
#pragma unroll
    for (int ni = 0; ni < 4; ni++) {
      int col = n0 + wc * 64 + ni * 16 + lr;
      float bv = bias ? bias[col] : 0.f;
#pragma unroll
      for (int jj = 0; jj < 4; jj++) {
        int row = m0 + wr * 64 + mi * 16 + lg * 4 + jj;
        float v = acc[mi][ni][jj] + bv;
        Cb[(size_t)row * N + col] = f2b(v);
      }
    }
}

// ---------------------------------------------------------------- flash attention (dual q-tile)
// r14 structure; ALiBi folded: scores kept in tile-relative domain, tile offset
// t = slope*kb applied to the running max only (math-identical, -34 VALU/proc).
__global__ __launch_bounds__(512, 4) void k_attn(const unsigned short* __restrict__ qkv,
                                                 unsigned short* __restrict__ o) {
  __shared__ unsigned short Ks[2][64][72];
  __shared__ unsigned short Vt[2][64][72];   // Vt[buf][d][swz(k)], swz: k-blk ^= (d>>3)
  __shared__ unsigned short Pl[8][16][72];
  const int tid = threadIdx.x, lane = tid & 63, w = tid >> 6;
  const int bh = blockIdx.x, b = bh >> 4, h = bh & 15;
  const int lr = lane & 15, lg = lane >> 4, lg4 = lg * 4;
  const int krow = tid >> 3, c8 = (tid & 7) << 3;
  const int kb8 = krow >> 3, kl = krow & 7, vq = tid & 7;
  const float slope2 = exp2f(-0.5f * (float)(h + 1)) * 1.44269504f;
  const float sc2 = 0.125f * 1.44269504f;

  // per-element ALiBi within a tile (tile-invariant): slope2 * (kn*16 + lg4 + jj)
  float alib0[4][4];
#pragma unroll
  for (int kn = 0; kn < 4; kn++)
#pragma unroll
    for (int jj = 0; jj < 4; jj++)
      alib0[kn][jj] = slope2 * (float)(kn * 16 + lg4 + jj);

  const int y = blockIdx.y;
  const int qloA = y * 128 + w * 16;
  const int qloB = (7 - y) * 128 + w * 16;
  const int qaA = qloA + lr, qaB = qloB + lr;

  bf16x8 qfA0, qfA1, qfB0, qfB1;
  {
    const unsigned short* qp = &qkv[(size_t)(b * 1024 + qloA + lr) * 3072 + h * 64];
    qfA0 = *reinterpret_cast<const bf16x8*>(qp + lg * 8);
    qfA1 = *reinterpret_cast<const bf16x8*>(qp + 32 + lg * 8);
    const unsigned short* qp2 = &qkv[(size_t)(b * 1024 + qloB + lr) * 3072 + h * 64];
    qfB0 = *reinterpret_cast<const bf16x8*>(qp2 + lg * 8);
    qfB1 = *reinterpret_cast<const bf16x8*>(qp2 + 32 + lg * 8);
  }
  float mrunA = -3.0e38f, lrunA = 0.f, mrunB = -3.0e38f, lrunB = 0.f;
  f32x4 accOA[4], accOB[4];
  for (int dn = 0; dn < 4; dn++)
    for (int e = 0; e < 4; e++) { accOA[dn][e] = 0.f; accOB[dn][e] = 0.f; }

  const int nt = 16 - 2 * y;

  auto proc = [&](int kb, int cb, int qlo, int qa, float& mrun, float& lrun,
                  f32x4 (&accO)[4], bf16x8 qf0, bf16x8 qf1) {
    f32x4 sf[4];
    for (int kn = 0; kn < 4; kn++) {
      f32x4 zz;
      for (int e = 0; e < 4; e++) zz[e] = 0.f;
      bf16x8 kf0 = *reinterpret_cast<const bf16x8*>(&Ks[cb][kn * 16 + lr][lg * 8]);
      bf16x8 kf1 = *reinterpret_cast<const bf16x8*>(&Ks[cb][kn * 16 + lr][32 + lg * 8]);
      zz = __builtin_amdgcn_mfma_f32_16x16x32_bf16(kf0, qf0, zz, 0, 0, 0);
      zz = __builtin_amdgcn_mfma_f32_16x16x32_bf16(kf1, qf1, zz, 0, 0, 0);
      sf[kn] = zz;
    }
    const bool needmask = (kb + 63 > qlo);
    const int qrel = qa - kb;                 // mask: crel > qrel
    const float t = slope2 * (float)kb;       // tile-uniform ALiBi offset
    float sc[4][4];
    float ml = -3.0e38f;                      // relative-domain max
    for (int kn = 0; kn < 4; kn++) {
      for (int jj = 0; jj < 4; jj++) {
        float v = fmaf(sf[kn][jj], sc2, alib0[kn][jj]);
        if (needmask && (kn * 16 + lg4 + jj > qrel)) v = -3.0e38f;
        sc[kn][jj] = v;
        ml = fmaxf(ml, v);
      }
    }
    ml = fmaxf(ml, __shfl_xor(ml, 16));
    ml = fmaxf(ml, __shfl_xor(ml, 32));
    float mnew = fmaxf(mrun, ml + t);         // absolute domain
    float f = exp2f(mrun - mnew);
    float msub = mnew - t;                    // relative threshold
    float rs = 0.f;
    for (int kn = 0; kn < 4; kn++) {
      __bf16 pb[4];
      for (int jj = 0; jj < 4; jj++) {
        float pv = exp2f(sc[kn][jj] - msub);
        rs += pv;
        pb[jj] = (__bf16)pv;
      }
      *reinterpret_cast<uint2*>(&Pl[w][lr][kn * 16 + lg4]) =
          *reinterpret_cast<uint2*>(pb);
    }
    rs += __shfl_xor(rs, 16);
    rs += __shfl_xor(rs, 32);
    lrun = lrun * f + rs;
    mrun = mnew;
    float fj[4];
    for (int jj = 0; jj < 4; jj++) fj[jj] = __shfl(f, (lane & 48) | (lg4 + jj));
    for (int dn = 0; dn < 4; dn++)
      for (int jj = 0; jj < 4; jj++) accO[dn][jj] *= fj[jj];
    asm volatile("s_waitcnt lgkmcnt(0)" ::: "memory");   // own P writes drained
    for (int ks = 0; ks < 2; ks++) {
      bf16x8 pa = *reinterpret_cast<const bf16x8*>(&Pl[w][lr][ks * 32 + lg * 8]);
      for (int dn = 0; dn < 4; dn++) {
        int d = dn * 16 + lr;
        bf16x8 vb = *reinterpret_cast<const bf16x8*>(
            &Vt[cb][d][(((ks * 4 + lg) ^ (d >> 3)) << 3)]);
        accO[dn] = __builtin_amdgcn_mfma_f32_16x16x32_bf16(pa, vb, accO[dn], 0, 0, 0);
      }
    }
  };

  uint4 kr, vr;
  {
    const size_t base = (size_t)(b * 1024 + krow) * 3072 + h * 64;
    kr = *reinterpret_cast<const uint4*>(&qkv[base + 1024 + c8]);
    vr = *reinterpret_cast<const uint4*>(&qkv[base + 2048 + c8]);
  }
  *reinterpret_cast<uint4*>(&Ks[0][krow][c8]) = kr;
  {
    const unsigned short* vs = reinterpret_cast<const unsigned short*>(&vr);
    for (int jj = 0; jj < 8; jj++)
      Vt[0][c8 + jj][((kb8 ^ vq) << 3) | kl] = vs[jj];
  }
  __syncthreads();

  for (int kt = 0; kt < nt; ++kt) {
    const int kb = kt << 6;
    const int cb = kt & 1, nb = cb ^ 1;
    const bool hn = (kt + 1 < nt);
    if (hn) {                               // issue global loads for tile t+1
      const size_t base = (size_t)(b * 1024 + kb + 64 + krow) * 3072 + h * 64;
      kr = *reinterpret_cast<const uint4*>(&qkv[base + 1024 + c8]);
      vr = *reinterpret_cast<const uint4*>(&qkv[base + 2048 + c8]);
    }
    if (kb <= qloA + 15)
      proc(kb, cb, qloA, qaA, mrunA, lrunA, accOA, qfA0, qfA1);
    if (hn) {                               // write buf for t+1 (overlapped)
      *reinterpret_cast<uint4*>(&Ks[nb][krow][c8]) = kr;
      const unsigned short* vs = reinterpret_cast<const unsigned short*>(&vr);
      for (int jj = 0; jj < 8; jj++)
        Vt[nb][c8 + jj][((kb8 ^ vq) << 3) | kl] = vs[jj];
    }
    if (kb <= qloB + 15)
      proc(kb, cb, qloB, qaB, mrunB, lrunB, accOB, qfB0, qfB1);
    __syncthreads();                        // single barrier per tile
  }

  float linvA[4], linvB[4];
  for (int jj = 0; jj < 4; jj++) {
    linvA[jj] = 1.f / __shfl(lrunA, (lane & 48) | (lg4 + jj));
    linvB[jj] = 1.f / __shfl(lrunB, (lane & 48) | (lg4 + jj));
  }
  for (int dn = 0; dn < 4; dn++)
    for (int jj = 0; jj < 4; jj++) {
      int d = dn * 16 + lr;
      int rowA = qloA + lg4 + jj;
      o[(size_t)(b * 1024 + rowA) * 1024 + h * 64 + d] = f2b(accOA[dn][jj] * linvA[jj]);
      int rowB = qloB + lg4 + jj;
      o[(size_t)(b * 1024 + rowB) * 1024 + h * 64 + d] = f2b(accOB[dn][jj] * linvB[jj]);
    }
}

// ---------------------------------------------------------------- fused decode: out = xres@dcw^T + ob@wcomb^T + bias2
// 512 single-wave blocks.
__global__ __launch_bounds__(64) void k_dec2(const unsigned short* __restrict__ xres,
                                             const unsigned short* __restrict__ ob,
                                             const unsigned short* __restrict__ dwb,
                                             const unsigned short* __restrict__ wcombb,
                                             const float* __restrict__ bias2,
                                             float* __restrict__ out) {
  const int lane = threadIdx.x & 63;
  const int lr = lane & 15, lg = lane >> 4;
  const int r0 = blockIdx.x * 16;
  f32x4 acc;
  for (int e = 0; e < 4; e++) acc[e] = 0.f;
  const unsigned short* arow1 = &xres[(size_t)(r0 + lr) * 1024];
  const unsigned short* arow2 = &ob[(size_t)(r0 + lr) * 1024];
  const unsigned short* brow1 = &dwb[(size_t)lr * 1024];
  const unsigned short* brow2 = &wcombb[(size_t)lr * 1024];
  for (int k0 = 0; k0 < 1024; k0 += 32) {
    bf16x8 a1 = *reinterpret_cast<const bf16x8*>(arow1 + k0 + lg * 8);
    bf16x8 b1 = *reinterpret_cast<const bf16x8*>(brow1 + k0 + lg * 8);
    acc = __builtin_amdgcn_mfma_f32_16x16x32_bf16(a1, b1, acc, 0, 0, 0);
    bf16x8 a2 = *reinterpret_cast<const bf16x8*>(arow2 + k0 + lg * 8);
    bf16x8 b2 = *reinterpret_cast<const bf16x8*>(brow2 + k0 + lg * 8);
    acc = __builtin_amdgcn_mfma_f32_16x16x32_bf16(a2, b2, acc, 0, 0, 0);
  }
  const int b = r0 >> 10;
  const int sl = (r0 & 1023) + lg * 4;
  float bias = bias2[lr];
  float4 res;
  res.x = acc[0] + bias; res.y = acc[1] + bias; res.z = acc[2] + bias; res.w = acc[3] + bias;
  *reinterpret_cast<float4*>(&out[(size_t)(b * 16 + lr) * 1024 + sl]) = res;
}

// ---------------------------------------------------------------- launcher
extern "C" void kernel_launch(void* const* d_in, const int* in_sizes, int n_in,
                              void* d_out, int out_size, void* d_ws, size_t ws_size,
                              hipStream_t stream) {
  (void)in_sizes; (void)n_in; (void)out_size;
  const float* z   = (const float*)d_in[0];
  const float* rt  = (const float*)d_in[1];
  const float* dnw = (const float*)d_in[2];
  const float* dnb = (const float*)d_in[3];
  const float* lng = (const float*)d_in[4];
  const float* lnb = (const float*)d_in[5];
  const float* wq  = (const float*)d_in[6];
  const float* bq  = (const float*)d_in[7];
  const float* wk  = (const float*)d_in[8];
  const float* bk  = (const float*)d_in[9];
  const float* wv  = (const float*)d_in[10];
  const float* bv  = (const float*)d_in[11];
  const float* wo  = (const float*)d_in[12];
  const float* bo  = (const float*)d_in[13];
  const float* dcw = (const float*)d_in[14];
  const float* dcb = (const float*)d_in[15];
  float* out = (float*)d_out;

  char* p = (char*)d_ws;
  unsigned short* xres  = (unsigned short*)p; p += (size_t)M * FDEC * 2;
  unsigned short* xn    = (unsigned short*)p; p += (size_t)M * FDEC * 2;
  unsigned short* w3    = (unsigned short*)p; p += (size_t)3 * FDEC * FDEC * 2;
  float* b3             = (float*)p;          p += (size_t)3 * FDEC * 4;
  unsigned short* qkv   = (unsigned short*)p; p += (size_t)M * 3 * FDEC * 2;
  unsigned short* ob    = (unsigned short*)p; p += (size_t)M * FDEC * 2;
  unsigned short* dwb   = (unsigned short*)p; p += (size_t)FD * FDEC * 2;
  unsigned short* wcombb= (unsigned short*)p; p += (size_t)FD * FDEC * 2;
  float* bias2          = (float*)p;          p += (size_t)FD * 4;
  float* za             = (float*)p;          p += (size_t)8 * 1024 * 4;
  unsigned short* wt16  = (unsigned short*)p; p += (size_t)16 * 1024 * 2;
  float* part           = (float*)p;          p += (size_t)64 * FD * FDEC * 4;
  if ((size_t)(p - (char*)d_ws) > ws_size) return;

  k_pre<<<5268, 256, 0, stream>>>(dnw, wq, wk, wv, wo, dcw, bq, bk, bv, bo, dcb, z,
                                  w3, dwb, b3, wt16, part, bias2, za);
  k_dln<<<2112, 256, 0, stream>>>(rt, za, dnb, lng, lnb, wt16, part, xres, xn, wcombb);
  k_gemm1<1><<<(M / 128) * (3 * FDEC / 128), 256, 0, stream>>>(xn, FDEC, w3, FDEC, FDEC, 3 * FDEC, b3, qkv);
  k_attn<<<dim3(Bn * H, 4), 512, 0, stream>>>(qkv, ob);
  k_dec2<<<M / 16, 64, 0, stream>>>(xres, ob, dwb, wcombb, bias2, out);
}

// Round 19
// 153.002 us; speedup vs baseline: 1.2347x; 1.2347x over previous
//
#include <hip/hip_runtime.h>

// ---------------------------------------------------------------- constants
static constexpr int Bn   = 8;
static constexpr int S    = 1024;
static constexpr int FT   = 16;
static constexpr int FDZ  = 768;
static constexpr int INK  = 784;   // FDZ + FT
static constexpr int FDEC = 1024;
static constexpr int M    = Bn * S;   // 8192 rows
static constexpr int H    = 16;
static constexpr int FD   = 16;

typedef __bf16 bf16x8 __attribute__((ext_vector_type(8)));
typedef float  f32x4  __attribute__((ext_vector_type(4)));

__device__ __forceinline__ unsigned short f2b(float f) {
  return __builtin_bit_cast(unsigned short, static_cast<__bf16>(f));
}
__device__ __forceinline__ float b2f(unsigned short u) {
  return (float)__builtin_bit_cast(__bf16, u);
}

__device__ __forceinline__ void gload16(const void* g, void* l) {
  __builtin_amdgcn_global_load_lds(
      (const __attribute__((address_space(1))) unsigned int*)g,
      (__attribute__((address_space(3))) unsigned int*)l, 16, 0, 0);
}

// ---------------------------------------------------------------- merged pre-pass (1 launch)
// [0,3072) w3 | [3072,3088) dwb | [3088,3091) b3 | [3091,3155) wt16 |
// [3155,3219) wcomb part | [3219] bias2 | [3220,5268) za
__global__ __launch_bounds__(256) void k_pre(const float* __restrict__ dnw,
                                             const float* __restrict__ wq,
                                             const float* __restrict__ wk,
                                             const float* __restrict__ wv,
                                             const float* __restrict__ wo,
                                             const float* __restrict__ dcw,
                                             const float* __restrict__ bq,
                                             const float* __restrict__ bk,
                                             const float* __restrict__ bv,
                                             const float* __restrict__ bo,
                                             const float* __restrict__ dcb,
                                             const float* __restrict__ z,
                                             unsigned short* __restrict__ w3,
                                             unsigned short* __restrict__ dwb,
                                             float* __restrict__ b3,
                                             unsigned short* __restrict__ wt16,
                                             float* __restrict__ part,
                                             float* __restrict__ bias2,
                                             float* __restrict__ za) {
  const int bid = blockIdx.x, tid = threadIdx.x;
  const int c = tid * 4;
  if (bid < 3072) {
    const int r = bid;
    const float* src = (r < 1024) ? wq : (r < 2048 ? wk : wv);
    const int rr = r & 1023;
    float4 v = *reinterpret_cast<const float4*>(&src[(size_t)rr * 1024 + c]);
    unsigned short o4[4] = {f2b(v.x), f2b(v.y), f2b(v.z), f2b(v.w)};
    *reinterpret_cast<uint2*>(&w3[(size_t)r * 1024 + c]) = *reinterpret_cast<uint2*>(o4);
  } else if (bid < 3088) {
    const int r = bid - 3072;
    float4 v = *reinterpret_cast<const float4*>(&dcw[(size_t)r * 1024 + c]);
    unsigned short o4[4] = {f2b(v.x), f2b(v.y), f2b(v.z), f2b(v.w)};
    *reinterpret_cast<uint2*>(&dwb[(size_t)r * 1024 + c]) = *reinterpret_cast<uint2*>(o4);
  } else if (bid < 3091) {
    const int r = bid - 3088;
    const float* s = (r == 0) ? bq : (r == 1 ? bk : bv);
    *reinterpret_cast<float4*>(&b3[r * 1024 + c]) =
        *reinterpret_cast<const float4*>(&s[c]);
  } else if (bid < 3155) {
    const int idx = (bid - 3091) * 256 + tid;   // 0..16383
    const int k = idx >> 10, cc = idx & 1023;
    wt16[k * 1024 + cc] = f2b(dnw[(size_t)cc * INK + k]);
  } else if (bid < 3219) {
    // wcomb stage 1, coalesced: part[kb][i][:] += dcw[i][16kb+k] * wo[16kb+k][:]
    const int kb = bid - 3155;
    const int k0 = kb * 16;
    float4 wv4[16];
#pragma unroll
    for (int k = 0; k < 16; k++)
      wv4[k] = *reinterpret_cast<const float4*>(&wo[(size_t)(k0 + k) * 1024 + c]);
#pragma unroll
    for (int i = 0; i < 16; i++) {
      float4 a = make_float4(0.f, 0.f, 0.f, 0.f);
#pragma unroll
      for (int k = 0; k < 16; k++) {
        float d = dcw[i * 1024 + k0 + k];   // uniform -> scalar load
        a.x += d * wv4[k].x; a.y += d * wv4[k].y;
        a.z += d * wv4[k].z; a.w += d * wv4[k].w;
      }
      *reinterpret_cast<float4*>(&part[((size_t)kb * 16 + i) * 1024 + c]) = a;
    }
  } else if (bid < 3220) {
    const int lane = tid & 63, w = tid >> 6;
    for (int q = 0; q < 4; q++) {
      int f = w * 4 + q;
      const float* dp = &dcw[(size_t)f * 1024];
      float s = 0.f;
#pragma unroll
      for (int t = 0; t < 16; t++) {
        int k = lane + t * 64;
        s += dp[k] * bo[k];
      }
      for (int off = 32; off; off >>= 1) s += __shfl_down(s, off);
      if (lane == 0) bias2[f] = s + dcb[f];
    }
  } else {
    const int lane = tid & 63, w = tid >> 6;
    const int idx = (bid - 3220) * 4 + w;        // 0..8191
    const int col = idx >> 3, b = idx & 7;
    const float* wp = &dnw[(size_t)col * INK + FT];
    const float* zp = &z[b * FDZ];
    float s = 0.f;
#pragma unroll
    for (int i = 0; i < 12; i++) {
      int k = lane + i * 64;
      s += wp[k] * zp[k];
    }
    for (int off = 32; off; off >>= 1) s += __shfl_down(s, off);
    if (lane == 0) za[b * 1024 + col] = s;
  }
}

// ---------------------------------------------------------------- dense(K=16)+LN  +  wcomb reduce
// bid < 2048: dense+LN (4 rows/block). bid in [2048,2112): wcomb stage-2 reduce.
__global__ __launch_bounds__(256) void k_dln(const float* __restrict__ rt,
                                             const float* __restrict__ za,
                                             const float* __restrict__ dnb,
                                             const float* __restrict__ lng,
                                             const float* __restrict__ lnb,
                                             const unsigned short* __restrict__ wt16g,
                                             const float* __restrict__ part,
                                             unsigned short* __restrict__ xres,
                                             unsigned short* __restrict__ xn,
                                             unsigned short* __restrict__ wcombb) {
  const int tid = threadIdx.x;
  if (blockIdx.x >= 2048) {
    const int idx = (blockIdx.x - 2048) * 256 + tid;   // 0..16383
    float s = 0.f;
#pragma unroll 8
    for (int kb = 0; kb < 64; kb++) s += part[(size_t)kb * 16384 + idx];
    wcombb[idx] = f2b(s);
    return;
  }
  __shared__ unsigned short wt[16 * 1024];     // [k][c] bf16, 32 KiB
  __shared__ float ss[4], qq[4];
  const int lane = tid & 63, wv = tid >> 6;
  const int c0 = tid * 4;
#pragma unroll
  for (int i = 0; i < 8; i++)
    reinterpret_cast<uint4*>(wt)[tid + 256 * i] =
        reinterpret_cast<const uint4*>(wt16g)[tid + 256 * i];
  const float4 bv  = *reinterpret_cast<const float4*>(&dnb[c0]);
  const float4 gv  = *reinterpret_cast<const float4*>(&lng[c0]);
  const float4 bev = *reinterpret_cast<const float4*>(&lnb[c0]);
  __syncthreads();

  for (int r = 0; r < 4; ++r) {
    const int m = blockIdx.x * 4 + r;
    const int b = m >> 10;
    float rtv[16];
    {
      float4 t0 = *reinterpret_cast<const float4*>(&rt[m * 16 + 0]);
      float4 t1 = *reinterpret_cast<const float4*>(&rt[m * 16 + 4]);
      float4 t2 = *reinterpret_cast<const float4*>(&rt[m * 16 + 8]);
      float4 t3 = *reinterpret_cast<const float4*>(&rt[m * 16 + 12]);
      rtv[0]=t0.x; rtv[1]=t0.y; rtv[2]=t0.z; rtv[3]=t0.w;
      rtv[4]=t1.x; rtv[5]=t1.y; rtv[6]=t1.z; rtv[7]=t1.w;
      rtv[8]=t2.x; rtv[9]=t2.y; rtv[10]=t2.z; rtv[11]=t2.w;
      rtv[12]=t3.x; rtv[13]=t3.y; rtv[14]=t3.z; rtv[15]=t3.w;
    }
    float4 zav = *reinterpret_cast<const float4*>(&za[b * 1024 + c0]);
    float acc[4] = {zav.x + bv.x, zav.y + bv.y, zav.z + bv.z, zav.w + bv.w};
#pragma unroll
    for (int k = 0; k < 16; ++k) {
      uint2 wraw = *reinterpret_cast<const uint2*>(&wt[k * 1024 + c0]);
      const unsigned short* wp = reinterpret_cast<const unsigned short*>(&wraw);
      float rk = rtv[k];
      acc[0] += rk * b2f(wp[0]);
      acc[1] += rk * b2f(wp[1]);
      acc[2] += rk * b2f(wp[2]);
      acc[3] += rk * b2f(wp[3]);
    }
    float s = acc[0] + acc[1] + acc[2] + acc[3];
    float q = acc[0]*acc[0] + acc[1]*acc[1] + acc[2]*acc[2] + acc[3]*acc[3];
    for (int off = 32; off; off >>= 1) { s += __shfl_down(s, off); q += __shfl_down(q, off); }
    if (lane == 0) { ss[wv] = s; qq[wv] = q; }
    __syncthreads();
    float St = ss[0] + ss[1] + ss[2] + ss[3];
    float Qt = qq[0] + qq[1] + qq[2] + qq[3];
    float mu  = St * (1.f / 1024.f);
    float var = Qt * (1.f / 1024.f) - mu * mu;
    float rstd = rsqrtf(var + 1e-6f);
    unsigned short xo[4], no[4];
    xo[0] = f2b(acc[0]); no[0] = f2b(gv.x * (acc[0] - mu) * rstd + bev.x);
    xo[1] = f2b(acc[1]); no[1] = f2b(gv.y * (acc[1] - mu) * rstd + bev.y);
    xo[2] = f2b(acc[2]); no[2] = f2b(gv.z * (acc[2] - mu) * rstd + bev.z);
    xo[3] = f2b(acc[3]); no[3] = f2b(gv.w * (acc[3] - mu) * rstd + bev.w);
    *reinterpret_cast<uint2*>(&xres[(size_t)m * 1024 + c0]) = *reinterpret_cast<uint2*>(xo);
    *reinterpret_cast<uint2*>(&xn[(size_t)m * 1024 + c0])   = *reinterpret_cast<uint2*>(no);
    __syncthreads();
  }
}

// ---------------------------------------------------------------- GEMM 128x128 (qkv)
template<int EPI>
__global__ __launch_bounds__(256, 3) void k_gemm1(const unsigned short* __restrict__ A, int lda,
                                                  const unsigned short* __restrict__ Bw, int ldb,
                                                  int K, int N,
                                                  const float* __restrict__ bias,
                                                  unsigned short* __restrict__ Cb) {
  __shared__ __align__(16) unsigned short As[3 * 128 * 32];   // 24 KiB
  __shared__ __align__(16) unsigned short Bs[3 * 128 * 32];   // 24 KiB
  const int tid = threadIdx.x, lane = tid & 63, w = tid >> 6;
  const int wr = w >> 1, wc = w & 1;
  const int lr = lane & 15, lg = lane >> 4;

  const int xcd = blockIdx.x & 7;
  const int j   = blockIdx.x >> 3;
  const int m0  = (xcd * 8 + (j & 7)) * 128;
  const int n0  = (j >> 3) * 128;

  const int nt = K >> 5;

  const int g0 = tid;
  const int r0g = g0 >> 2, c0g = (g0 & 3) ^ ((r0g >> 1) & 3);
  const int g1 = tid + 256;
  const int r1g = g1 >> 2, c1g = (g1 & 3) ^ ((r1g >> 1) & 3);
  const unsigned short* srcA0 = A + (size_t)(m0 + r0g) * lda + c0g * 8;
  const unsigned short* srcA1 = A + (size_t)(m0 + r1g) * lda + c1g * 8;
  const unsigned short* srcB0 = Bw + (size_t)(n0 + r0g) * ldb + c0g * 8;
  const unsigned short* srcB1 = Bw + (size_t)(n0 + r1g) * ldb + c1g * 8;
  const int d0 = (w * 64) * 8;
  const int d1 = (256 + w * 64) * 8;

  int offA[4], offB[4];
#pragma unroll
  for (int mi = 0; mi < 4; mi++) {
    int r = wr * 64 + mi * 16 + lr;
    offA[mi] = r * 32 + (lg ^ ((r >> 1) & 3)) * 8;
  }
#pragma unroll
  for (int ni = 0; ni < 4; ni++) {
    int r = wc * 64 + ni * 16 + lr;
    offB[ni] = r * 32 + (lg ^ ((r >> 1) & 3)) * 8;
  }

  f32x4 acc[4][4];
#pragma unroll
  for (int i = 0; i < 4; i++)
#pragma unroll
    for (int j2 = 0; j2 < 4; j2++)
#pragma unroll
      for (int e = 0; e < 4; e++) acc[i][j2][e] = 0.f;

  auto stage = [&](int tt) {
    const int sl = tt % 3;
    const size_t ko = (size_t)tt * 32;
    gload16(srcA0 + ko, &As[sl * 4096 + d0]);
    gload16(srcA1 + ko, &As[sl * 4096 + d1]);
    gload16(srcB0 + ko, &Bs[sl * 4096 + d0]);
    gload16(srcB1 + ko, &Bs[sl * 4096 + d1]);
  };
  auto compute = [&](int tt) {
    const int sl = (tt % 3) * 4096;
    bf16x8 af[4], bfr[4];
#pragma unroll
    for (int mi = 0; mi < 4; mi++)
      af[mi] = *reinterpret_cast<const bf16x8*>(&As[sl + offA[mi]]);
#pragma unroll
    for (int ni = 0; ni < 4; ni++)
      bfr[ni] = *reinterpret_cast<const bf16x8*>(&Bs[sl + offB[ni]]);
    __builtin_amdgcn_s_setprio(1);
#pragma unroll
    for (int mi = 0; mi < 4; mi++)
#pragma unroll
      for (int ni = 0; ni < 4; ni++)
        acc[mi][ni] = __builtin_amdgcn_mfma_f32_16x16x32_bf16(af[mi], bfr[ni], acc[mi][ni], 0, 0, 0);
    __builtin_amdgcn_s_setprio(0);
  };

  stage(0); stage(1);

  int t = 0;
  for (; t < nt - 2; ++t) {
    asm volatile("s_waitcnt vmcnt(4)" ::: "memory");
    __builtin_amdgcn_s_barrier();
    stage(t + 2);
    compute(t);
  }
  asm volatile("s_waitcnt vmcnt(4)" ::: "memory");
  __builtin_amdgcn_s_barrier();
  compute(t); ++t;
  asm volatile("s_waitcnt vmcnt(0)" ::: "memory");
  __builtin_amdgcn_s_barrier();
  compute(t);

#pragma unroll
  for (int mi = 0; mi < 4; mi++)
#pragma unroll
    for (int ni = 0; ni < 4; ni++) {
      int col = n0 + wc * 64 + ni * 16 + lr;
      float bv = bias ? bias[col] : 0.f;
#pragma unroll
      for (int jj = 0; jj < 4; jj++) {
        int row = m0 + wr * 64 + mi * 16 + lg * 4 + jj;
        float v = acc[mi][ni][jj] + bv;
        Cb[(size_t)row * N + col] = f2b(v);
      }
    }
}

// ---------------------------------------------------------------- flash attention (dual q-tile, r14 exact)
__global__ __launch_bounds__(512, 4) void k_attn(const unsigned short* __restrict__ qkv,
                                                 unsigned short* __restrict__ o) {
  __shared__ unsigned short Ks[2][64][72];
  __shared__ unsigned short Vt[2][64][72];   // Vt[buf][d][swz(k)], swz: k-blk ^= (d>>3)
  __shared__ unsigned short Pl[8][16][72];
  const int tid = threadIdx.x, lane = tid & 63, w = tid >> 6;
  const int bh = blockIdx.x, b = bh >> 4, h = bh & 15;
  const int lr = lane & 15, lg = lane >> 4, lg4 = lg * 4;
  const int krow = tid >> 3, c8 = (tid & 7) << 3;
  const int kb8 = krow >> 3, kl = krow & 7, vq = tid & 7;
  const float slope2 = exp2f(-0.5f * (float)(h + 1)) * 1.44269504f;
  const float sc2 = 0.125f * 1.44269504f;

  const int y = blockIdx.y;
  const int qloA = y * 128 + w * 16;
  const int qloB = (7 - y) * 128 + w * 16;
  const int qaA = qloA + lr, qaB = qloB + lr;

  bf16x8 qfA0, qfA1, qfB0, qfB1;
  {
    const unsigned short* qp = &qkv[(size_t)(b * 1024 + qloA + lr) * 3072 + h * 64];
    qfA0 = *reinterpret_cast<const bf16x8*>(qp + lg * 8);
    qfA1 = *reinterpret_cast<const bf16x8*>(qp + 32 + lg * 8);
    const unsigned short* qp2 = &qkv[(size_t)(b * 1024 + qloB + lr) * 3072 + h * 64];
    qfB0 = *reinterpret_cast<const bf16x8*>(qp2 + lg * 8);
    qfB1 = *reinterpret_cast<const bf16x8*>(qp2 + 32 + lg * 8);
  }
  float mrunA = -3.0e38f, lrunA = 0.f, mrunB = -3.0e38f, lrunB = 0.f;
  f32x4 accOA[4], accOB[4];
  for (int dn = 0; dn < 4; dn++)
    for (int e = 0; e < 4; e++) { accOA[dn][e] = 0.f; accOB[dn][e] = 0.f; }

  const int nt = 16 - 2 * y;

  auto proc = [&](int kb, int cb, int qlo, int qa, float& mrun, float& lrun,
                  f32x4 (&accO)[4], bf16x8 qf0, bf16x8 qf1) {
    f32x4 sf[4];
    for (int kn = 0; kn < 4; kn++) {
      f32x4 zz;
      for (int e = 0; e < 4; e++) zz[e] = 0.f;
      bf16x8 kf0 = *reinterpret_cast<const bf16x8*>(&Ks[cb][kn * 16 + lr][lg * 8]);
      bf16x8 kf1 = *reinterpret_cast<const bf16x8*>(&Ks[cb][kn * 16 + lr][32 + lg * 8]);
      zz = __builtin_amdgcn_mfma_f32_16x16x32_bf16(kf0, qf0, zz, 0, 0, 0);
      zz = __builtin_amdgcn_mfma_f32_16x16x32_bf16(kf1, qf1, zz, 0, 0, 0);
      sf[kn] = zz;
    }
    const bool needmask = (kb + 63 > qlo);
    float sc[4][4];
    float ml = -3.0e38f;
    for (int kn = 0; kn < 4; kn++) {
      float alib = slope2 * (float)(kb + kn * 16 + lg4);
      for (int jj = 0; jj < 4; jj++) {
        float v = fmaf(sf[kn][jj], sc2, alib + slope2 * (float)jj);
        if (needmask && (kb + kn * 16 + lg4 + jj > qa)) v = -3.0e38f;
        sc[kn][jj] = v;
        ml = fmaxf(ml, v);
      }
    }
    ml = fmaxf(ml, __shfl_xor(ml, 16));
    ml = fmaxf(ml, __shfl_xor(ml, 32));
    float mnew = fmaxf(mrun, ml);
    float f = exp2f(mrun - mnew);
    float rs = 0.f;
    for (int kn = 0; kn < 4; kn++) {
      __bf16 pb[4];
      for (int jj = 0; jj < 4; jj++) {
        float pv = exp2f(sc[kn][jj] - mnew);
        rs += pv;
        pb[jj] = (__bf16)pv;
      }
      *reinterpret_cast<uint2*>(&Pl[w][lr][kn * 16 + lg4]) =
          *reinterpret_cast<uint2*>(pb);
    }
    rs += __shfl_xor(rs, 16);
    rs += __shfl_xor(rs, 32);
    lrun = lrun * f + rs;
    mrun = mnew;
    float fj[4];
    for (int jj = 0; jj < 4; jj++) fj[jj] = __shfl(f, (lane & 48) | (lg4 + jj));
    for (int dn = 0; dn < 4; dn++)
      for (int jj = 0; jj < 4; jj++) accO[dn][jj] *= fj[jj];
    asm volatile("s_waitcnt lgkmcnt(0)" ::: "memory");   // own P writes drained
    for (int ks = 0; ks < 2; ks++) {
      bf16x8 pa = *reinterpret_cast<const bf16x8*>(&Pl[w][lr][ks * 32 + lg * 8]);
      for (int dn = 0; dn < 4; dn++) {
        int d = dn * 16 + lr;
        bf16x8 vb = *reinterpret_cast<const bf16x8*>(
            &Vt[cb][d][(((ks * 4 + lg) ^ (d >> 3)) << 3)]);
        accO[dn] = __builtin_amdgcn_mfma_f32_16x16x32_bf16(pa, vb, accO[dn], 0, 0, 0);
      }
    }
  };

  uint4 kr, vr;
  {
    const size_t base = (size_t)(b * 1024 + krow) * 3072 + h * 64;
    kr = *reinterpret_cast<const uint4*>(&qkv[base + 1024 + c8]);
    vr = *reinterpret_cast<const uint4*>(&qkv[base + 2048 + c8]);
  }
  *reinterpret_cast<uint4*>(&Ks[0][krow][c8]) = kr;
  {
    const unsigned short* vs = reinterpret_cast<const unsigned short*>(&vr);
    for (int jj = 0; jj < 8; jj++)
      Vt[0][c8 + jj][((kb8 ^ vq) << 3) | kl] = vs[jj];
  }
  __syncthreads();

  for (int kt = 0; kt < nt; ++kt) {
    const int kb = kt << 6;
    const int cb = kt & 1, nb = cb ^ 1;
    const bool hn = (kt + 1 < nt);
    if (hn) {                               // issue global loads for tile t+1
      const size_t base = (size_t)(b * 1024 + kb + 64 + krow) * 3072 + h * 64;
      kr = *reinterpret_cast<const uint4*>(&qkv[base + 1024 + c8]);
      vr = *reinterpret_cast<const uint4*>(&qkv[base + 2048 + c8]);
    }
    if (kb <= qloA + 15)
      proc(kb, cb, qloA, qaA, mrunA, lrunA, accOA, qfA0, qfA1);
    if (hn) {                               // write buf for t+1 (overlapped)
      *reinterpret_cast<uint4*>(&Ks[nb][krow][c8]) = kr;
      const unsigned short* vs = reinterpret_cast<const unsigned short*>(&vr);
      for (int jj = 0; jj < 8; jj++)
        Vt[nb][c8 + jj][((kb8 ^ vq) << 3) | kl] = vs[jj];
    }
    if (kb <= qloB + 15)
      proc(kb, cb, qloB, qaB, mrunB, lrunB, accOB, qfB0, qfB1);
    __syncthreads();                        // single barrier per tile
  }

  float linvA[4], linvB[4];
  for (int jj = 0; jj < 4; jj++) {
    linvA[jj] = 1.f / __shfl(lrunA, (lane & 48) | (lg4 + jj));
    linvB[jj] = 1.f / __shfl(lrunB, (lane & 48) | (lg4 + jj));
  }
  for (int dn = 0; dn < 4; dn++)
    for (int jj = 0; jj < 4; jj++) {
      int d = dn * 16 + lr;
      int rowA = qloA + lg4 + jj;
      o[(size_t)(b * 1024 + rowA) * 1024 + h * 64 + d] = f2b(accOA[dn][jj] * linvA[jj]);
      int rowB = qloB + lg4 + jj;
      o[(size_t)(b * 1024 + rowB) * 1024 + h * 64 + d] = f2b(accOB[dn][jj] * linvB[jj]);
    }
}

// ---------------------------------------------------------------- fused decode: out = xres@dcw^T + ob@wcomb^T + bias2
// 512 single-wave blocks.
__global__ __launch_bounds__(64) void k_dec2(const unsigned short* __restrict__ xres,
                                             const unsigned short* __restrict__ ob,
                                             const unsigned short* __restrict__ dwb,
                                             const unsigned short* __restrict__ wcombb,
                                             const float* __restrict__ bias2,
                                             float* __restrict__ out) {
  const int lane = threadIdx.x & 63;
  const int lr = lane & 15, lg = lane >> 4;
  const int r0 = blockIdx.x * 16;
  f32x4 acc;
  for (int e = 0; e < 4; e++) acc[e] = 0.f;
  const unsigned short* arow1 = &xres[(size_t)(r0 + lr) * 1024];
  const unsigned short* arow2 = &ob[(size_t)(r0 + lr) * 1024];
  const unsigned short* brow1 = &dwb[(size_t)lr * 1024];
  const unsigned short* brow2 = &wcombb[(size_t)lr * 1024];
  for (int k0 = 0; k0 < 1024; k0 += 32) {
    bf16x8 a1 = *reinterpret_cast<const bf16x8*>(arow1 + k0 + lg * 8);
    bf16x8 b1 = *reinterpret_cast<const bf16x8*>(brow1 + k0 + lg * 8);
    acc = __builtin_amdgcn_mfma_f32_16x16x32_bf16(a1, b1, acc, 0, 0, 0);
    bf16x8 a2 = *reinterpret_cast<const bf16x8*>(arow2 + k0 + lg * 8);
    bf16x8 b2 = *reinterpret_cast<const bf16x8*>(brow2 + k0 + lg * 8);
    acc = __builtin_amdgcn_mfma_f32_16x16x32_bf16(a2, b2, acc, 0, 0, 0);
  }
  const int b = r0 >> 10;
  const int sl = (r0 & 1023) + lg * 4;
  float bias = bias2[lr];
  float4 res;
  res.x = acc[0] + bias; res.y = acc[1] + bias; res.z = acc[2] + bias; res.w = acc[3] + bias;
  *reinterpret_cast<float4*>(&out[(size_t)(b * 16 + lr) * 1024 + sl]) = res;
}

// ---------------------------------------------------------------- launcher
extern "C" void kernel_launch(void* const* d_in, const int* in_sizes, int n_in,
                              void* d_out, int out_size, void* d_ws, size_t ws_size,
                              hipStream_t stream) {
  (void)in_sizes; (void)n_in; (void)out_size;
  const float* z   = (const float*)d_in[0];
  const float* rt  = (const float*)d_in[1];
  const float* dnw = (const float*)d_in[2];
  const float* dnb = (const float*)d_in[3];
  const float* lng = (const float*)d_in[4];
  const float* lnb = (const float*)d_in[5];
  const float* wq  = (const float*)d_in[6];
  const float* bq  = (const float*)d_in[7];
  const float* wk  = (const float*)d_in[8];
  const float* bk  = (const float*)d_in[9];
  const float* wv  = (const float*)d_in[10];
  const float* bv  = (const float*)d_in[11];
  const float* wo  = (const float*)d_in[12];
  const float* bo  = (const float*)d_in[13];
  const float* dcw = (const float*)d_in[14];
  const float* dcb = (const float*)d_in[15];
  float* out = (float*)d_out;

  char* p = (char*)d_ws;
  unsigned short* xres  = (unsigned short*)p; p += (size_t)M * FDEC * 2;
  unsigned short* xn    = (unsigned short*)p; p += (size_t)M * FDEC * 2;
  unsigned short* w3    = (unsigned short*)p; p += (size_t)3 * FDEC * FDEC * 2;
  float* b3             = (float*)p;          p += (size_t)3 * FDEC * 4;
  unsigned short* qkv   = (unsigned short*)p; p += (size_t)M * 3 * FDEC * 2;
  unsigned short* ob    = (unsigned short*)p; p += (size_t)M * FDEC * 2;
  unsigned short* dwb   = (unsigned short*)p; p += (size_t)FD * FDEC * 2;
  unsigned short* wcombb= (unsigned short*)p; p += (size_t)FD * FDEC * 2;
  float* bias2          = (float*)p;          p += (size_t)FD * 4;
  float* za             = (float*)p;          p += (size_t)8 * 1024 * 4;
  unsigned short* wt16  = (unsigned short*)p; p += (size_t)16 * 1024 * 2;
  float* part           = (float*)p;          p += (size_t)64 * FD * FDEC * 4;
  if ((size_t)(p - (char*)d_ws) > ws_size) return;

  k_pre<<<5268, 256, 0, stream>>>(dnw, wq, wk, wv, wo, dcw, bq, bk, bv, bo, dcb, z,
                                  w3, dwb, b3, wt16, part, bias2, za);
  k_dln<<<2112, 256, 0, stream>>>(rt, za, dnb, lng, lnb, wt16, part, xres, xn, wcombb);
  k_gemm1<1><<<(M / 128) * (3 * FDEC / 128), 256, 0, stream>>>(xn, FDEC, w3, FDEC, FDEC, 3 * FDEC, b3, qkv);
  k_attn<<<dim3(Bn * H, 4), 512, 0, stream>>>(qkv, ob);
  k_dec2<<<M / 16, 64, 0, stream>>>(xres, ob, dwb, wcombb, bias2, out);
}